// Round 4
// baseline (106.636 us; speedup 1.0000x reference)
//
#include <hip/hip_runtime.h>
#include <math.h>

// Match numpy (no FMA fusion) for all decision-critical arithmetic.
#pragma clang fp contract(off)

#define IMG_H 240
#define IMG_W 320
#define NPX   (IMG_H * IMG_W)
#define NCH   11
#define NSLICE 8       // face-dim parallelism: grid.z slices (interleaved chunks)
#define CULL_M 1e-3f   // conservative SAT-cull margin (e-units; |err| <~ 1e-5)
#define EZ_M   1e-5f   // early-z margin (>> 4e-7 fp bound on depth vs min(pz))
#define NBIN   256

struct ProjM { float m[16]; };   // row-major numpy proj (after row-1 flip)

// Conservative depth bin: L(b) = b/128 - 1 is guaranteed <= zm (explicit
// decrement fixes the fp-rounding case where (zm+1)*128 rounds up past an
// integer). zm=+inf -> bin 255; NaN -> bin 0 (harmless, gated elsewhere).
__device__ __forceinline__ int zbin(float zm) {
  float t = fminf(fmaxf((zm + 1.0f) * 128.0f, 0.0f), 255.0f);
  int b = (int)t;
  if ((float)b * 0.0078125f - 1.0f > zm) b = (b > 0) ? b - 1 : 0;
  return b;
}

// Init: zero vnacc (needed by k_face atomics), hist, binctr.
extern "C" __global__ void k_init(float* __restrict__ vnacc, int n3v,
                                  int* __restrict__ hist,
                                  int* __restrict__ binctr) {
  int i = blockIdx.x * 256 + threadIdx.x;
  if (i < n3v) vnacc[i] = 0.0f;
  if (i < NBIN) { hist[i] = 0; binctr[i] = 0; }
}

// Shared transform helper — EXACT reference DAG (contract off).
__device__ __forceinline__ void xform(float x, float y, float z,
                                      const float* __restrict__ pose,
                                      const ProjM& P,
                                      float& px, float& py, float& pz,
                                      float& iw, float& wc) {
  float c0 = ((x*pose[0]     + y*pose[1])     + z*pose[2])     + pose[3];
  float c1 = ((x*(-pose[4])  + y*(-pose[5]))  + z*(-pose[6]))  + (-pose[7]);
  float c2 = ((x*(-pose[8])  + y*(-pose[9]))  + z*(-pose[10])) + (-pose[11]);
  float c3 = ((x*pose[12]    + y*pose[13])    + z*pose[14])    + pose[15];
  float q0 = ((c0*P.m[0]  + c1*P.m[1])  + c2*P.m[2])  + c3*P.m[3];
  float q1 = ((c0*P.m[4]  + c1*P.m[5])  + c2*P.m[6])  + c3*P.m[7];
  float q2 = ((c0*P.m[8]  + c1*P.m[9])  + c2*P.m[10]) + c3*P.m[11];
  float q3 = ((c0*P.m[12] + c1*P.m[13]) + c2*P.m[14]) + c3*P.m[15];
  wc = q3;
  float denw = (fabsf(wc) > 1e-9f) ? wc : 1e-9f;
  iw = 1.0f / denw;
  float ndx = q0 * iw, ndy = q1 * iw;
  pz = q2 * iw;
  px = ((ndx + 1.0f) * 0.5f) * (float)IMG_W;
  py = ((1.0f - ndy) * 0.5f) * (float)IMG_H;
}

// Fused per-face kernel (grid widened to 300x256 so every thread also
// clears one zkey slot — zkey is first read by k_rasterA, two dispatches
// later, so no ordering hazard). Emits face-normal atomics, face records,
// fzmin = min(pz) and the depth-bin histogram for the front-to-back sort.
//
// Reference's e0/e1/e2 are NOT standard barycentrics:
//   e0 = -lambda_A, e1 = -lambda_B, e2 = 2 - lambda_C; accepted region
//   {e>=0} is the triangle point-reflected through vertex C. Culling uses
//   (a) that region's bbox and (b) fp64-derived affine edge coefficients.
// frec layout (16 floats, 64 B) — eval side, reference DAG operands:
//   [0..3]  bx, by, d0=(cy-by), d1=(cx-bx)
//   [4..7]  cx, cy, d2=(ay-cy), d3=(ax-cx)
//   [8..11] inva, pz0, pz1, pz2
//   [12..15] iw0, iw1, iw2, 0
extern "C" __global__ void k_face(const float* __restrict__ verts,
                                  const int* __restrict__ faces,
                                  const float* __restrict__ pose,
                                  ProjM P,
                                  float* __restrict__ vnacc,
                                  float4* __restrict__ frec,
                                  float4* __restrict__ fbb,
                                  float4* __restrict__ fe,
                                  int4*  __restrict__ fidx,
                                  float* __restrict__ fzmin,
                                  int*   __restrict__ hist,
                                  unsigned long long* __restrict__ zkey,
                                  int F) {
  int f = blockIdx.x * 256 + threadIdx.x;
  if (f < NPX) zkey[f] = ~0ull;
  if (f >= F) return;
  int i0 = faces[3*f+0], i1 = faces[3*f+1], i2 = faces[3*f+2];
  float x0 = verts[3*i0+0], y0 = verts[3*i0+1], z0 = verts[3*i0+2];
  float x1 = verts[3*i1+0], y1 = verts[3*i1+1], z1 = verts[3*i1+2];
  float x2 = verts[3*i2+0], y2 = verts[3*i2+1], z2 = verts[3*i2+2];

  // ---- face normal accumulation (unchanged DAG) ----
  {
    float ux = x1 - x0, uy = y1 - y0, uz = z1 - z0;
    float vx = x2 - x0, vy = y2 - y0, vz = z2 - z0;
    float fx = uy*vz - uz*vy;
    float fy = uz*vx - ux*vz;
    float fz = ux*vy - uy*vx;
    float n = sqrtf((fx*fx + fy*fy) + fz*fz);
    float d = fmaxf(n, 1e-12f);
    fx = fx / d; fy = fy / d; fz = fz / d;
    atomicAdd(&vnacc[3*i0+0], fx); atomicAdd(&vnacc[3*i0+1], fy); atomicAdd(&vnacc[3*i0+2], fz);
    atomicAdd(&vnacc[3*i1+0], fx); atomicAdd(&vnacc[3*i1+1], fy); atomicAdd(&vnacc[3*i1+2], fz);
    atomicAdd(&vnacc[3*i2+0], fx); atomicAdd(&vnacc[3*i2+1], fy); atomicAdd(&vnacc[3*i2+2], fz);
  }

  // ---- corner transforms (identical DAG to reference vertex path) ----
  float ax, ay, pz0, iw0, w0;  xform(x0, y0, z0, pose, P, ax, ay, pz0, iw0, w0);
  float bx, by, pz1, iw1, w1;  xform(x1, y1, z1, pose, P, bx, by, pz1, iw1, w1);
  float cx, cy, pz2, iw2, w2;  xform(x2, y2, z2, pose, P, cx, cy, pz2, iw2, w2);

  float area = (bx - ax) * (cy - ay) - (by - ay) * (cx - ax);
  float inva = 1.0f / ((fabsf(area) > 1e-12f) ? area : 1e-12f);
  bool valid = (w0 > 1e-6f) && (w1 > 1e-6f) && (w2 > 1e-6f) && (fabsf(area) > 1e-12f);
  // reflected-triangle vertices {C, 2C-A, 2C-B}
  float rax = 2.0f*cx - ax, ray = 2.0f*cy - ay;
  float rbx = 2.0f*cx - bx, rby = 2.0f*cy - by;
  float minx = fminf(cx, fminf(rax, rbx)), maxx = fmaxf(cx, fmaxf(rax, rbx));
  float miny = fminf(cy, fminf(ray, rby)), maxy = fmaxf(cy, fmaxf(ray, rby));
  frec[4*f+0] = make_float4(bx, by, cy - by, cx - bx);
  frec[4*f+1] = make_float4(cx, cy, ay - cy, ax - cx);
  frec[4*f+2] = make_float4(inva, pz0, pz1, pz2);
  frec[4*f+3] = make_float4(iw0, iw1, iw2, 0.0f);
  fbb[f] = valid ? make_float4(minx, maxx, miny, maxy)
                 : make_float4(1e30f, -1e30f, 1e30f, -1e30f);
  fidx[f] = make_int4(i0, i1, i2, 0);

  // front-to-back sort key: min NDC depth (depth at any covered pixel is a
  // convex combination of pz0..2, so depth >= zmin). Invalid faces -> +inf.
  float zm = valid ? fminf(pz0, fminf(pz1, pz2)) : __builtin_huge_valf();
  fzmin[f] = zm;
  atomicAdd(&hist[zbin(zm)], 1);

  // affine edge coefficients, fp64 for tight error:
  //   e0 = ((X-bx)*d0 - (Y-by)*d1)*inva = a0*X + b0*Y + c0
  {
    double dbx = bx, dby = by, dcx = cx, dcy = cy, dax = ax, day = ay;
    double dinv = (double)inva;
    double d0 = dcy - dby, d1 = dcx - dbx;
    double d2 = day - dcy, d3 = dax - dcx;
    double a0 = d0 * dinv, b0 = -d1 * dinv, c0 = (dby * d1 - dbx * d0) * dinv;
    double a1 = d2 * dinv, b1 = -d3 * dinv, c1 = (dcy * d3 - dcx * d2) * dinv;
    fe[2*f+0] = make_float4((float)a0, (float)b0, (float)c0, 0.0f);
    fe[2*f+1] = make_float4((float)a1, (float)b1, (float)c1, 0.0f);
  }
}

// Counting-sort scatter with the 256-bin exclusive scan REDUNDANTLY
// recomputed per block in LDS. Allocation within a bin via the shared
// binctr atomics. Emits, in approximate front-to-back order:
//   forig[pos]   original face id
//   szmin[pos]   exact zmin (per-face early-z gate, shuffled from registers)
//   smon[pos]    bin floor L(bin) — MONOTONE nondecreasing lower bound on
//                all zmin at positions >= pos (exact-safe break condition)
//   fbbs/fes     reordered cull records; frecs: reordered eval records
// Order within a bin is nondeterministic; the final winner is the
// lexicographic (depth, original index) atomicMin — order-independent.
extern "C" __global__ void k_scatter(const float* __restrict__ fzmin,
                                     const int* __restrict__ hist,
                                     int* __restrict__ binctr,
                                     const float4* __restrict__ fbb,
                                     const float4* __restrict__ fe,
                                     const float4* __restrict__ frec,
                                     int*   __restrict__ forig,
                                     float* __restrict__ szmin,
                                     float* __restrict__ smon,
                                     float4* __restrict__ fbbs,
                                     float4* __restrict__ fes,
                                     float4* __restrict__ frecs, int F) {
  __shared__ int s[NBIN];
  __shared__ int ex[NBIN];
  int t = threadIdx.x;
  int v = hist[t];
  s[t] = v;
  __syncthreads();
  for (int o = 1; o < NBIN; o <<= 1) {
    int x = (t >= o) ? s[t - o] : 0;
    __syncthreads();
    s[t] += x;
    __syncthreads();
  }
  ex[t] = s[t] - v;   // exclusive scan
  __syncthreads();

  int f = blockIdx.x * 256 + t;
  if (f >= F) return;
  float zm = fzmin[f];
  int b = zbin(zm);
  int pos = ex[b] + atomicAdd(&binctr[b], 1);
  forig[pos] = f;
  szmin[pos] = zm;
  smon[pos]  = (float)b * 0.0078125f - 1.0f;
  fbbs[pos]  = fbb[f];
  fes[2*pos+0] = fe[2*f+0];
  fes[2*pos+1] = fe[2*f+1];
  frecs[4*pos+0] = frec[4*f+0];
  frecs[4*pos+1] = frec[4*f+1];
  frecs[4*pos+2] = frec[4*f+2];
  frecs[4*pos+3] = frec[4*f+3];
}

// Pass A: 16x16 pixel region per 256-thread block (4 waves x 8x8 subtiles).
// Faces consumed front-to-back (sorted by zmin); grid.z slices take
// INTERLEAVED 64-face chunks so every slice starts near the front.
//
// ALL pruning state is in REGISTERS (round-3 lesson: per-chunk zkey atomic
// loads cost ~39 MB of serialized L2 traffic = the whole regression).
// Pruning layers (every skip requires a >= EZ_M gap = 25x the fp depth-
// error bound, so exact ties are never skipped):
//  1. chunk BREAK: pbm (wave-max own bestd) <= smon[base]-EZ_M
//  2. per-lane cull gate: szmin[i] < pbm+EZ_M before bbox/SAT
//  3. per-PAIR ballot gate on min(zmin) — registers only, before any load
// Survivor loop unrolled x2 so the 6 wave-uniform scalar loads of both
// faces issue before either eval (halves exposed L2 latency).
// Tie semantics: accept on (depth,origIdx) lexicographic improvement;
// single final packed-u64 atomicMin — the reference argmin+strict-<.
extern "C" __global__ __launch_bounds__(256)
void k_rasterA(const float4* __restrict__ frecs,
               const float4* __restrict__ fbbs,
               const float4* __restrict__ fes,
               const int*    __restrict__ forig,
               const float*  __restrict__ szmin,
               const float*  __restrict__ smon,
               unsigned long long* __restrict__ zkey,
               int F) {
  int t = threadIdx.x;
  int wave = t >> 6;                  // 0..3
  int lane = t & 63;
  int sx = (wave & 1) * 8, sy = (wave >> 1) * 8;
  int pxi = blockIdx.x * 16 + sx + (lane & 7);
  int pyi = blockIdx.y * 16 + sy + (lane >> 3);
  float X = (float)pxi + 0.5f;
  float Y = (float)pyi + 0.5f;
  float tXlo = (float)(blockIdx.x * 16 + sx) + 0.5f, tXhi = tXlo + 7.0f;
  float tYlo = (float)(blockIdx.y * 16 + sy) + 0.5f, tYhi = tYlo + 7.0f;
  size_t pix = (size_t)pyi * IMG_W + pxi;

  float bestd = 1.0f + 1.0e-3f;       // depth must be <= 1.0 to win
  int   besti = -1;

  int nchunk = (F + 63) >> 6;
  for (int c = blockIdx.z; c < nchunk; c += NSLICE) {
    int base = c << 6;

    // wave-max prune bound from own bestd (registers only)
    float pbm = bestd;
    #pragma unroll
    for (int o = 32; o > 0; o >>= 1) pbm = fmaxf(pbm, __shfl_xor(pbm, o));

    // all faces at positions >= base have zmin >= smon[base] (monotone bin
    // floors) -> none can produce depth <= bestd for any lane: done.
    if (pbm <= smon[base] - EZ_M) break;

    int i = base + lane;
    // per-chunk register stage: sorted zmin + original id for this lane's face
    float szlane = __builtin_huge_valf();
    int   folane = 0;
    bool ov = false;
    if (i < F) {
      szlane = szmin[i];
      folane = forig[i];
      if (szlane < pbm + EZ_M) {   // depth-gate before bbox/SAT
        float4 bb = fbbs[i];
        ov = (bb.x - 1.0f <= tXhi) && (bb.y + 1.0f >= tXlo) &&
             (bb.z - 1.0f <= tYhi) && (bb.w + 1.0f >= tYlo);
        if (ov) {
          float4 E0 = fes[2*i+0];
          float4 E1 = fes[2*i+1];
          float pa0 = E0.x * tXlo, pb0 = E0.x * tXhi;
          float qa0 = E0.y * tYlo, qb0 = E0.y * tYhi;
          float e0mx = (fmaxf(pa0, pb0) + fmaxf(qa0, qb0)) + E0.z;
          float pa1 = E1.x * tXlo, pb1 = E1.x * tXhi;
          float qa1 = E1.y * tYlo, qb1 = E1.y * tYhi;
          float e1mx = (fmaxf(pa1, pb1) + fmaxf(qa1, qb1)) + E1.z;
          float e0mn = (fminf(pa0, pb0) + fminf(qa0, qb0)) + E0.z;
          float e1mn = (fminf(pa1, pb1) + fminf(qa1, qb1)) + E1.z;
          float e2mx = (1.0f - e0mn) - e1mn;   // upper bound of e2 = 1-e0-e1
          ov = (e0mx >= -CULL_M) && (e1mx >= -CULL_M) && (e2mx >= -CULL_M);
        }
      }
    }
    unsigned long long mask = __ballot(ov);

    while (mask) {
      int j0 = __builtin_ctzll(mask);
      mask &= mask - 1;
      bool two = (mask != 0ull);
      int j1 = two ? __builtin_ctzll(mask) : j0;   // pad with duplicate
      if (two) mask &= mask - 1;

      // per-pair early-z from registers (no memory): conservative min zmin
      float zm0 = __shfl(szlane, j0);
      float zm1 = __shfl(szlane, j1);
      float zmg = fminf(zm0, zm1);
      if (__ballot(bestd > zmg - EZ_M) == 0ull) continue;

      int jj0 = __builtin_amdgcn_readfirstlane(base + j0);
      int jj1 = __builtin_amdgcn_readfirstlane(base + j1);
      int fo0 = __builtin_amdgcn_readfirstlane(__shfl(folane, j0));
      int fo1 = __builtin_amdgcn_readfirstlane(__shfl(folane, j1));
      const float4* fr0 = frecs + (size_t)jj0 * 4;
      const float4* fr1 = frecs + (size_t)jj1 * 4;
      // issue ALL scalar loads before either eval (latency overlap)
      float4 A0 = fr0[0], B0 = fr0[1], C0 = fr0[2];
      float4 A1 = fr1[0], B1 = fr1[1], C1 = fr1[2];

      {
        float t0 = (X - A0.x) * A0.z;
        float t1 = (Y - A0.y) * A0.w;
        float e0 = (t0 - t1) * C0.x;
        float t2 = (X - B0.x) * B0.z;
        float t3 = (Y - B0.y) * B0.w;
        float e1 = (t2 - t3) * C0.x;
        float e2 = (1.0f - e0) - e1;
        float depth = ((e0 * C0.y) + (e1 * C0.z)) + (e2 * C0.w);
        bool inside = (e0 >= 0.0f) && (e1 >= 0.0f) && (e2 >= 0.0f) &&
                      (depth >= -1.0f) && (depth <= 1.0f);
        if (inside && (depth < bestd || (depth == bestd && fo0 < besti))) {
          bestd = depth; besti = fo0;
        }
      }
      if (two) {
        float t0 = (X - A1.x) * A1.z;
        float t1 = (Y - A1.y) * A1.w;
        float e0 = (t0 - t1) * C1.x;
        float t2 = (X - B1.x) * B1.z;
        float t3 = (Y - B1.y) * B1.w;
        float e1 = (t2 - t3) * C1.x;
        float e2 = (1.0f - e0) - e1;
        float depth = ((e0 * C1.y) + (e1 * C1.z)) + (e2 * C1.w);
        bool inside = (e0 >= 0.0f) && (e1 >= 0.0f) && (e2 >= 0.0f) &&
                      (depth >= -1.0f) && (depth <= 1.0f);
        if (inside && (depth < bestd || (depth == bestd && fo1 < besti))) {
          bestd = depth; besti = fo1;
        }
      }
    }
  }

  // single commit (round-0 structure): atomicMin resolves cross-slice
  if (besti >= 0) {
    unsigned int ub = __float_as_uint(bestd);
    ub = (ub & 0x80000000u) ? ~ub : (ub | 0x80000000u);   // order-preserving
    unsigned long long key = ((unsigned long long)ub << 32) | (unsigned int)besti;
    atomicMin(&zkey[pix], key);
  }
}

// Pass B: per-pixel resolve — recompute winner's barycentrics (same DAG as
// rasterA, via ORIGINAL-order frec keyed by the packed original index) and
// compute the 3 winner-vertex colors INLINE (bit-identical DAG to the old
// k_vertex). Stage in LDS, write fully-coalesced float4s.
extern "C" __global__ __launch_bounds__(256)
void k_resolve(const unsigned long long* __restrict__ zkey,
               const float4* __restrict__ frec,
               const int4* __restrict__ fidx,
               const float* __restrict__ verts,
               const float* __restrict__ vnacc,
               const float* __restrict__ pose,
               float* __restrict__ out) {
  __shared__ float sOut[256 * NCH];   // 11 KB
  int t = threadIdx.x;
  int p = blockIdx.x * 256 + t;       // NPX = 300 * 256 exactly
  int pyi = p / IMG_W, pxi = p - pyi * IMG_W;
  float X = (float)pxi + 0.5f;
  float Y = (float)pyi + 0.5f;
  unsigned long long key = zkey[p];

  float oc[NCH];
  if (key != ~0ull) {
    int besti = (int)(key & 0xFFFFFFFFu);
    const float4* fr = frec + (size_t)besti * 4;
    float4 A = fr[0], B = fr[1], C = fr[2], D = fr[3];
    float t0 = (X - A.x) * A.z;
    float t1 = (Y - A.y) * A.w;
    float e0 = (t0 - t1) * C.x;
    float t2 = (X - B.x) * B.z;
    float t3 = (Y - B.y) * B.w;
    float e1 = (t2 - t3) * C.x;
    float b2 = (1.0f - e0) - e1;
    float p0 = e0 * D.x, p1 = e1 * D.y, p2 = b2 * D.z;
    float den = (p0 + p1) + p2;
    if (!(fabsf(den) > 1e-12f)) den = 1e-12f;
    float u0 = p0 / den, u1 = p1 / den, u2 = p2 / den;
    int4 vi = fidx[besti];

    // inline vertex colors (exact old-k_vertex DAG), 3 vertices
    float cv[3][NCH];
    int vids[3] = { vi.x, vi.y, vi.z };
    #pragma unroll
    for (int k = 0; k < 3; ++k) {
      int id = vids[k];
      float x = verts[3*id+0], y = verts[3*id+1], z = verts[3*id+2];
      float nx = vnacc[3*id+0], ny = vnacc[3*id+1], nz = vnacc[3*id+2];
      float nn = sqrtf((nx*nx + ny*ny) + nz*nz);
      float nm = fmaxf(nn, 1e-12f);
      nx = nx / nm; ny = ny / nm; nz = nz / nm;
      float v3x = ((x*pose[0] + y*pose[1]) + z*pose[2])  + pose[3];
      float v3y = ((x*pose[4] + y*pose[5]) + z*pose[6])  + pose[7];
      float v3z = ((x*pose[8] + y*pose[9]) + z*pose[10]) + pose[11];
      cv[k][0] = 1.0f;  cv[k][1] = v3x; cv[k][2] = v3y; cv[k][3] = v3z;
      cv[k][4] = nx;    cv[k][5] = ny;  cv[k][6] = nz;
      cv[k][7] = x;     cv[k][8] = y;   cv[k][9] = z;   cv[k][10] = 1.0f;
    }
    #pragma unroll
    for (int ch = 0; ch < NCH; ++ch)
      oc[ch] = (u0 * cv[0][ch] + u1 * cv[1][ch]) + u2 * cv[2][ch];
  } else {
    #pragma unroll
    for (int ch = 0; ch < NCH; ++ch) oc[ch] = 0.0f;
  }
  #pragma unroll
  for (int ch = 0; ch < NCH; ++ch) sOut[t * NCH + ch] = oc[ch];
  __syncthreads();
  // 256*11 = 2816 floats = 704 float4s, contiguous; block offset 16B-aligned
  float4* o4 = (float4*)(out + (size_t)blockIdx.x * 256 * NCH);
  const float4* s4 = (const float4*)sOut;
  #pragma unroll
  for (int k = 0; k < 3; ++k) {
    int idx = t + k * 256;
    if (idx < 704) o4[idx] = s4[idx];
  }
}

extern "C" void kernel_launch(void* const* d_in, const int* in_sizes, int n_in,
                              void* d_out, int out_size, void* d_ws, size_t ws_size,
                              hipStream_t stream) {
  const float* verts = (const float*)d_in[0];
  const int*   faces = (const int*)d_in[1];
  const float* pose  = (const float*)d_in[2];
  float* out = (float*)d_out;
  int V = in_sizes[0] / 3;
  int F = in_sizes[1] / 3;

  // workspace layout (float units, 16B-aligned chunks)
  float* ws = (float*)d_ws;
  size_t o = 0;
  auto alloc = [&](size_t n) { size_t r = o; o += (n + 3) & ~(size_t)3; return r; };
  size_t o_zk   = alloc((size_t)2 * NPX);     // u64 zkey buffer
  size_t o_vn   = alloc((size_t)3 * V);
  size_t o_fr   = alloc((size_t)16 * F);
  size_t o_bb   = alloc((size_t)4 * F);
  size_t o_fe   = alloc((size_t)8 * F);
  size_t o_fi   = alloc((size_t)4 * F);
  size_t o_fz   = alloc((size_t)F);           // fzmin
  size_t o_hist = alloc((size_t)NBIN);        // int histogram
  size_t o_bc   = alloc((size_t)NBIN);        // int bin alloc counters
  size_t o_fo   = alloc((size_t)F);           // forig (sorted -> orig id)
  size_t o_sz   = alloc((size_t)F);           // szmin (sorted)
  size_t o_sm   = alloc((size_t)F);           // smon (monotone bin floors)
  size_t o_bbs  = alloc((size_t)4 * F);       // fbb sorted
  size_t o_fes  = alloc((size_t)8 * F);       // fe sorted
  size_t o_frs  = alloc((size_t)16 * F);      // frec sorted (eval records)
  unsigned long long* zkey = (unsigned long long*)(ws + o_zk);
  float*  vnacc = ws + o_vn;
  float4* frec  = (float4*)(ws + o_fr);
  float4* fbb   = (float4*)(ws + o_bb);
  float4* fe    = (float4*)(ws + o_fe);
  int4*   fidx  = (int4*)(ws + o_fi);
  float*  fzmin = ws + o_fz;
  int*    hist  = (int*)(ws + o_hist);
  int*    binctr= (int*)(ws + o_bc);
  int*    forig = (int*)(ws + o_fo);
  float*  szmin = ws + o_sz;
  float*  smon  = ws + o_sm;
  float4* fbbs  = (float4*)(ws + o_bbs);
  float4* fes   = (float4*)(ws + o_fes);
  float4* frecs = (float4*)(ws + o_frs);

  // projection matrix: double math then f32 cast, matching numpy
  double fxd = 286.2057, sd = 0.0, cxd = 162.6306;
  double fyd = 286.7852, cyd = 121.0245;
  double wd = IMG_W, hd = IMG_H, ncd = 0.1, fcd = 10.0;
  double q  = -(fcd + ncd) / (fcd - ncd);
  double qn = -2.0 * fcd * ncd / (fcd - ncd);
  double Pd[16] = {
    2.0*fxd/wd, -2.0*sd/wd, (-2.0*cxd + wd)/wd, 0.0,
    0.0,        2.0*fyd/hd, (2.0*cyd - hd)/hd, -0.0,
    0.0,        0.0,        q,                  qn,
    0.0,        0.0,       -1.0,                0.0 };
  ProjM P;
  for (int i = 0; i < 16; ++i) P.m[i] = (float)Pd[i];

  int n3v = 3 * V;
  k_init<<<(n3v + 255) / 256, 256, 0, stream>>>(vnacc, n3v, hist, binctr);
  int gface = ((NPX > F ? NPX : F) + 255) / 256;   // widened: also clears zkey
  k_face<<<gface, 256, 0, stream>>>(verts, faces, pose, P, vnacc,
                                    frec, fbb, fe, fidx, fzmin, hist, zkey, F);
  k_scatter<<<(F + 255) / 256, 256, 0, stream>>>(fzmin, hist, binctr, fbb, fe,
                                                 frec, forig, szmin, smon,
                                                 fbbs, fes, frecs, F);
  dim3 g(IMG_W / 16, IMG_H / 16, NSLICE);
  k_rasterA<<<g, 256, 0, stream>>>(frecs, fbbs, fes, forig, szmin, smon, zkey, F);
  k_resolve<<<NPX / 256, 256, 0, stream>>>(zkey, frec, fidx, verts, vnacc,
                                           pose, out);
}

// Round 5
// 90.636 us; speedup vs baseline: 1.1765x; 1.1765x over previous
//
#include <hip/hip_runtime.h>
#include <math.h>

// Match numpy (no FMA fusion) for all decision-critical arithmetic.
#pragma clang fp contract(off)

#define IMG_H 240
#define IMG_W 320
#define NPX   (IMG_H * IMG_W)
#define NCH   11
#define NCHP  12       // padded color stride (3 x float4)
#define NSLICE 16      // face-dim parallelism: grid.z slices (contiguous)
#define CULL_M 1e-3f   // conservative SAT-cull margin (e-units; |err| <~ 1e-5)
#define EZ_M   1e-5f   // early-z margin (>> 4e-7 fp bound on depth vs min(pz))

struct ProjM { float m[16]; };   // row-major numpy proj (after row-1 flip)

// One init dispatch: zero vnacc, set zkey buffer to "empty" (all 1s).
extern "C" __global__ void k_init(float* __restrict__ vnacc, int n3v,
                                  unsigned long long* __restrict__ zkey) {
  int i = blockIdx.x * 256 + threadIdx.x;
  if (i < n3v) vnacc[i] = 0.0f;
  if (i < NPX) zkey[i] = ~0ull;
}

// Shared transform helper — EXACT reference DAG (contract off).
__device__ __forceinline__ void xform(float x, float y, float z,
                                      const float* __restrict__ pose,
                                      const ProjM& P,
                                      float& px, float& py, float& pz,
                                      float& iw, float& wc) {
  float c0 = ((x*pose[0]     + y*pose[1])     + z*pose[2])     + pose[3];
  float c1 = ((x*(-pose[4])  + y*(-pose[5]))  + z*(-pose[6]))  + (-pose[7]);
  float c2 = ((x*(-pose[8])  + y*(-pose[9]))  + z*(-pose[10])) + (-pose[11]);
  float c3 = ((x*pose[12]    + y*pose[13])    + z*pose[14])    + pose[15];
  float q0 = ((c0*P.m[0]  + c1*P.m[1])  + c2*P.m[2])  + c3*P.m[3];
  float q1 = ((c0*P.m[4]  + c1*P.m[5])  + c2*P.m[6])  + c3*P.m[7];
  float q2 = ((c0*P.m[8]  + c1*P.m[9])  + c2*P.m[10]) + c3*P.m[11];
  float q3 = ((c0*P.m[12] + c1*P.m[13]) + c2*P.m[14]) + c3*P.m[15];
  wc = q3;
  float denw = (fabsf(wc) > 1e-9f) ? wc : 1e-9f;
  iw = 1.0f / denw;
  float ndx = q0 * iw, ndy = q1 * iw;
  pz = q2 * iw;
  px = ((ndx + 1.0f) * 0.5f) * (float)IMG_W;
  py = ((1.0f - ndy) * 0.5f) * (float)IMG_H;
}

// Fused per-face kernel: face-normal atomics + face setup (recomputes its 3
// corner transforms directly — bit-identical to a per-vertex pass since the
// expression DAG is identical and contraction is off).
//
// Reference's e0/e1/e2 are NOT standard barycentrics:
//   e0 = -lambda_A, e1 = -lambda_B, e2 = 2 - lambda_C; accepted region
//   {e>=0} is the triangle point-reflected through vertex C. Culling uses
//   (a) that region's bbox and (b) fp64-derived affine edge coefficients.
// frec layout (16 floats, 64 B) — eval side, reference DAG operands:
//   [0..3]  bx, by, d0=(cy-by), d1=(cx-bx)
//   [4..7]  cx, cy, d2=(ay-cy), d3=(ax-cx)
//   [8..11] inva, pz0, pz1, pz2
//   [12..15] iw0, iw1, iw2, 0
extern "C" __global__ void k_face(const float* __restrict__ verts,
                                  const int* __restrict__ faces,
                                  const float* __restrict__ pose,
                                  ProjM P,
                                  float* __restrict__ vnacc,
                                  float4* __restrict__ frec,
                                  float4* __restrict__ fbb,
                                  float4* __restrict__ fe,
                                  int4*  __restrict__ fidx, int F) {
  int f = blockIdx.x * 64 + threadIdx.x;
  if (f >= F) return;
  int i0 = faces[3*f+0], i1 = faces[3*f+1], i2 = faces[3*f+2];
  float x0 = verts[3*i0+0], y0 = verts[3*i0+1], z0 = verts[3*i0+2];
  float x1 = verts[3*i1+0], y1 = verts[3*i1+1], z1 = verts[3*i1+2];
  float x2 = verts[3*i2+0], y2 = verts[3*i2+1], z2 = verts[3*i2+2];

  // ---- face normal accumulation (unchanged DAG) ----
  {
    float ux = x1 - x0, uy = y1 - y0, uz = z1 - z0;
    float vx = x2 - x0, vy = y2 - y0, vz = z2 - z0;
    float fx = uy*vz - uz*vy;
    float fy = uz*vx - ux*vz;
    float fz = ux*vy - uy*vx;
    float n = sqrtf((fx*fx + fy*fy) + fz*fz);
    float d = fmaxf(n, 1e-12f);
    fx = fx / d; fy = fy / d; fz = fz / d;
    atomicAdd(&vnacc[3*i0+0], fx); atomicAdd(&vnacc[3*i0+1], fy); atomicAdd(&vnacc[3*i0+2], fz);
    atomicAdd(&vnacc[3*i1+0], fx); atomicAdd(&vnacc[3*i1+1], fy); atomicAdd(&vnacc[3*i1+2], fz);
    atomicAdd(&vnacc[3*i2+0], fx); atomicAdd(&vnacc[3*i2+1], fy); atomicAdd(&vnacc[3*i2+2], fz);
  }

  // ---- corner transforms (identical DAG to reference vertex path) ----
  float ax, ay, pz0, iw0, w0;  xform(x0, y0, z0, pose, P, ax, ay, pz0, iw0, w0);
  float bx, by, pz1, iw1, w1;  xform(x1, y1, z1, pose, P, bx, by, pz1, iw1, w1);
  float cx, cy, pz2, iw2, w2;  xform(x2, y2, z2, pose, P, cx, cy, pz2, iw2, w2);

  float area = (bx - ax) * (cy - ay) - (by - ay) * (cx - ax);
  float inva = 1.0f / ((fabsf(area) > 1e-12f) ? area : 1e-12f);
  bool valid = (w0 > 1e-6f) && (w1 > 1e-6f) && (w2 > 1e-6f) && (fabsf(area) > 1e-12f);
  // reflected-triangle vertices {C, 2C-A, 2C-B}
  float rax = 2.0f*cx - ax, ray = 2.0f*cy - ay;
  float rbx = 2.0f*cx - bx, rby = 2.0f*cy - by;
  float minx = fminf(cx, fminf(rax, rbx)), maxx = fmaxf(cx, fmaxf(rax, rbx));
  float miny = fminf(cy, fminf(ray, rby)), maxy = fmaxf(cy, fmaxf(ray, rby));
  frec[4*f+0] = make_float4(bx, by, cy - by, cx - bx);
  frec[4*f+1] = make_float4(cx, cy, ay - cy, ax - cx);
  frec[4*f+2] = make_float4(inva, pz0, pz1, pz2);
  frec[4*f+3] = make_float4(iw0, iw1, iw2, 0.0f);
  fbb[f] = valid ? make_float4(minx, maxx, miny, maxy)
                 : make_float4(1e30f, -1e30f, 1e30f, -1e30f);
  fidx[f] = make_int4(i0, i1, i2, 0);
  // affine edge coefficients, fp64 for tight error:
  //   e0 = ((X-bx)*d0 - (Y-by)*d1)*inva = a0*X + b0*Y + c0
  {
    double dbx = bx, dby = by, dcx = cx, dcy = cy, dax = ax, day = ay;
    double dinv = (double)inva;
    double d0 = dcy - dby, d1 = dcx - dbx;
    double d2 = day - dcy, d3 = dax - dcx;
    double a0 = d0 * dinv, b0 = -d1 * dinv, c0 = (dby * d1 - dbx * d0) * dinv;
    double a1 = d2 * dinv, b1 = -d3 * dinv, c1 = (dcy * d3 - dcx * d2) * dinv;
    fe[2*f+0] = make_float4((float)a0, (float)b0, (float)c0, 0.0f);
    fe[2*f+1] = make_float4((float)a1, (float)b1, (float)c1, 0.0f);
  }
}

// Per-vertex: normalize accumulated normal, world-space position, colors.
// Colors padded to stride 12 -> three float4 stores/loads.
extern "C" __global__ void k_vertex(const float* __restrict__ verts,
                                    const float* __restrict__ vnacc,
                                    const float* __restrict__ pose,
                                    float4* __restrict__ colors, int V) {
  int i = blockIdx.x * 64 + threadIdx.x;
  if (i >= V) return;
  float x = verts[3*i+0], y = verts[3*i+1], z = verts[3*i+2];

  float nx = vnacc[3*i+0], ny = vnacc[3*i+1], nz = vnacc[3*i+2];
  float nn = sqrtf((nx*nx + ny*ny) + nz*nz);
  float nm = fmaxf(nn, 1e-12f);
  nx = nx / nm; ny = ny / nm; nz = nz / nm;

  float v3x = ((x*pose[0] + y*pose[1]) + z*pose[2])  + pose[3];
  float v3y = ((x*pose[4] + y*pose[5]) + z*pose[6])  + pose[7];
  float v3z = ((x*pose[8] + y*pose[9]) + z*pose[10]) + pose[11];

  colors[3*i+0] = make_float4(1.0f, v3x, v3y, v3z);   // ch 0..3
  colors[3*i+1] = make_float4(nx, ny, nz, x);         // ch 4..7
  colors[3*i+2] = make_float4(y, z, 1.0f, 0.0f);      // ch 8..10, pad
}

// Pass A: 16x16 pixel region per 256-thread block (4 waves x 8x8 subtiles),
// face-slice on grid.z (contiguous ranges). No LDS, no barriers. Per 64-face
// chunk, lane j culls face j: reflected-bbox test + SAT via affine edge
// extrema at tile corners. Ballot -> survivors are wave-uniform, records
// read on the scalar path.
//
// Survivor loop processes TWO survivors per iteration: both C-records
// (inva,pz0..2) are issued together, the early-z ballot gate uses the
// conservative min of both zmins (skip only if NO lane can beat EITHER
// face — exact-safe), then both A/B record pairs issue together. This
// halves the exposed L2 scalar-load latency that dominates the serial
// scan (round-4 finding: the scan is latency-bound, not gate-bound).
// Faces are processed in ascending index order (j0 < j1, eval0 before
// eval1), so the strict-< accept keeps the reference's chunk-argmin +
// strict-< carry semantics. Winner = lexicographic min of (depth, face)
// via packed u64 atomicMin.
extern "C" __global__ __launch_bounds__(256)
void k_rasterA(const float4* __restrict__ frec,
               const float4* __restrict__ fbb,
               const float4* __restrict__ fe,
               unsigned long long* __restrict__ zkey,
               int F, int nslice) {
  int t = threadIdx.x;
  int wave = t >> 6;                  // 0..3
  int lane = t & 63;
  int sx = (wave & 1) * 8, sy = (wave >> 1) * 8;
  int pxi = blockIdx.x * 16 + sx + (lane & 7);
  int pyi = blockIdx.y * 16 + sy + (lane >> 3);
  float X = (float)pxi + 0.5f;
  float Y = (float)pyi + 0.5f;
  float tXlo = (float)(blockIdx.x * 16 + sx) + 0.5f, tXhi = tXlo + 7.0f;
  float tYlo = (float)(blockIdx.y * 16 + sy) + 0.5f, tYhi = tYlo + 7.0f;

  int f0 = blockIdx.z * nslice;
  int f1 = min(F, f0 + nslice);

  float bestd = 1e9f;
  int   besti = -1;

  for (int base = f0; base < f1; base += 64) {
    int f = base + lane;
    bool ov = false;
    if (f < f1) {
      float4 bb = fbb[f];
      ov = (bb.x - 1.0f <= tXhi) && (bb.y + 1.0f >= tXlo) &&
           (bb.z - 1.0f <= tYhi) && (bb.w + 1.0f >= tYlo);
      if (ov) {
        float4 E0 = fe[2*f+0];
        float4 E1 = fe[2*f+1];
        float pa0 = E0.x * tXlo, pb0 = E0.x * tXhi;
        float qa0 = E0.y * tYlo, qb0 = E0.y * tYhi;
        float e0mx = (fmaxf(pa0, pb0) + fmaxf(qa0, qb0)) + E0.z;
        float e0mn = (fminf(pa0, pb0) + fminf(qa0, qb0)) + E0.z;
        float pa1 = E1.x * tXlo, pb1 = E1.x * tXhi;
        float qa1 = E1.y * tYlo, qb1 = E1.y * tYhi;
        float e1mx = (fmaxf(pa1, pb1) + fmaxf(qa1, qb1)) + E1.z;
        float e1mn = (fminf(pa1, pb1) + fminf(qa1, qb1)) + E1.z;
        float e2mx = (1.0f - e0mn) - e1mn;   // upper bound of e2 = 1-e0-e1
        ov = (e0mx >= -CULL_M) && (e1mx >= -CULL_M) && (e2mx >= -CULL_M);
      }
    }
    unsigned long long mask = __ballot(ov);

    while (mask) {
      int j0 = __builtin_ctzll(mask);
      mask &= mask - 1;
      bool two = (mask != 0ull);
      int j1 = two ? __builtin_ctzll(mask) : j0;   // pad with duplicate
      if (two) mask &= mask - 1;

      int ju0 = __builtin_amdgcn_readfirstlane(base + j0);   // wave-uniform
      int ju1 = __builtin_amdgcn_readfirstlane(base + j1);
      const float4* fr0 = frec + (size_t)ju0 * 4;
      const float4* fr1 = frec + (size_t)ju1 * 4;
      // issue both depth records together (latency overlap)
      float4 C0 = fr0[2];   // inva, pz0, pz1, pz2
      float4 C1 = fr1[2];
      // early-z: no lane can beat a face whose min depth >= its bestd.
      // Gate on the conservative min of the pair — skip only if BOTH
      // faces provably lose for every lane.
      float zmin0 = fminf(C0.y, fminf(C0.z, C0.w));
      float zmin1 = fminf(C1.y, fminf(C1.z, C1.w));
      float zmg = two ? fminf(zmin0, zmin1) : zmin0;
      if (__ballot(bestd > zmg - EZ_M) == 0ull) continue;
      // issue both A/B record pairs together
      float4 A0 = fr0[0], B0 = fr0[1];
      float4 A1 = fr1[0], B1 = fr1[1];

      {
        float t0 = (X - A0.x) * A0.z;
        float t1 = (Y - A0.y) * A0.w;
        float e0 = (t0 - t1) * C0.x;
        float t2 = (X - B0.x) * B0.z;
        float t3 = (Y - B0.y) * B0.w;
        float e1 = (t2 - t3) * C0.x;
        float e2 = (1.0f - e0) - e1;
        float depth = ((e0 * C0.y) + (e1 * C0.z)) + (e2 * C0.w);
        bool inside = (e0 >= 0.0f) && (e1 >= 0.0f) && (e2 >= 0.0f) &&
                      (depth >= -1.0f) && (depth <= 1.0f);
        if (inside && depth < bestd) { bestd = depth; besti = ju0; }
      }
      if (two) {
        float t0 = (X - A1.x) * A1.z;
        float t1 = (Y - A1.y) * A1.w;
        float e0 = (t0 - t1) * C1.x;
        float t2 = (X - B1.x) * B1.z;
        float t3 = (Y - B1.y) * B1.w;
        float e1 = (t2 - t3) * C1.x;
        float e2 = (1.0f - e0) - e1;
        float depth = ((e0 * C1.y) + (e1 * C1.z)) + (e2 * C1.w);
        bool inside = (e0 >= 0.0f) && (e1 >= 0.0f) && (e2 >= 0.0f) &&
                      (depth >= -1.0f) && (depth <= 1.0f);
        if (inside && depth < bestd) { bestd = depth; besti = ju1; }
      }
    }
  }

  if (besti >= 0) {
    unsigned int ub = __float_as_uint(bestd);
    ub = (ub & 0x80000000u) ? ~ub : (ub | 0x80000000u);   // order-preserving
    unsigned long long key = ((unsigned long long)ub << 32) | (unsigned int)besti;
    atomicMin(&zkey[(size_t)pyi * IMG_W + pxi], key);
  }
}

// Pass B: per-pixel resolve — recompute winner's barycentrics (same DAG as
// rasterA), interpolate with vectorized color loads, stage in LDS, write
// fully-coalesced float4s.
extern "C" __global__ __launch_bounds__(256)
void k_resolve(const unsigned long long* __restrict__ zkey,
               const float4* __restrict__ frec,
               const float4* __restrict__ colors,
               const int4* __restrict__ fidx,
               float* __restrict__ out) {
  __shared__ float sOut[256 * NCH];   // 11 KB
  int t = threadIdx.x;
  int p = blockIdx.x * 256 + t;       // NPX = 300 * 256 exactly
  int pyi = p / IMG_W, pxi = p - pyi * IMG_W;
  float X = (float)pxi + 0.5f;
  float Y = (float)pyi + 0.5f;
  unsigned long long key = zkey[p];

  float oc[NCH];
  if (key != ~0ull) {
    int besti = (int)(key & 0xFFFFFFFFu);
    const float4* fr = frec + (size_t)besti * 4;
    float4 A = fr[0], B = fr[1], C = fr[2], D = fr[3];
    float t0 = (X - A.x) * A.z;
    float t1 = (Y - A.y) * A.w;
    float e0 = (t0 - t1) * C.x;
    float t2 = (X - B.x) * B.z;
    float t3 = (Y - B.y) * B.w;
    float e1 = (t2 - t3) * C.x;
    float b2 = (1.0f - e0) - e1;
    float p0 = e0 * D.x, p1 = e1 * D.y, p2 = b2 * D.z;
    float den = (p0 + p1) + p2;
    if (!(fabsf(den) > 1e-12f)) den = 1e-12f;
    float u0 = p0 / den, u1 = p1 / den, u2 = p2 / den;
    int4 vi = fidx[besti];
    float c0v[NCHP], c1v[NCHP], c2v[NCHP];
    #pragma unroll
    for (int k = 0; k < 3; ++k) {
      *(float4*)(c0v + 4*k) = colors[3*vi.x + k];
      *(float4*)(c1v + 4*k) = colors[3*vi.y + k];
      *(float4*)(c2v + 4*k) = colors[3*vi.z + k];
    }
    #pragma unroll
    for (int ch = 0; ch < NCH; ++ch)
      oc[ch] = (u0 * c0v[ch] + u1 * c1v[ch]) + u2 * c2v[ch];
  } else {
    #pragma unroll
    for (int ch = 0; ch < NCH; ++ch) oc[ch] = 0.0f;
  }
  #pragma unroll
  for (int ch = 0; ch < NCH; ++ch) sOut[t * NCH + ch] = oc[ch];
  __syncthreads();
  // 256*11 = 2816 floats = 704 float4s, contiguous; block offset 16B-aligned
  float4* o4 = (float4*)(out + (size_t)blockIdx.x * 256 * NCH);
  const float4* s4 = (const float4*)sOut;
  #pragma unroll
  for (int k = 0; k < 3; ++k) {
    int idx = t + k * 256;
    if (idx < 704) o4[idx] = s4[idx];
  }
}

extern "C" void kernel_launch(void* const* d_in, const int* in_sizes, int n_in,
                              void* d_out, int out_size, void* d_ws, size_t ws_size,
                              hipStream_t stream) {
  const float* verts = (const float*)d_in[0];
  const int*   faces = (const int*)d_in[1];
  const float* pose  = (const float*)d_in[2];
  float* out = (float*)d_out;
  int V = in_sizes[0] / 3;
  int F = in_sizes[1] / 3;

  // workspace layout (float units, 16B-aligned chunks)
  float* ws = (float*)d_ws;
  size_t o = 0;
  auto alloc = [&](size_t n) { size_t r = o; o += (n + 3) & ~(size_t)3; return r; };
  size_t o_zk   = alloc((size_t)2 * NPX);     // u64 zkey buffer
  size_t o_vn   = alloc((size_t)3 * V);
  size_t o_col  = alloc((size_t)NCHP * V);
  size_t o_fr   = alloc((size_t)16 * F);
  size_t o_bb   = alloc((size_t)4 * F);
  size_t o_fe   = alloc((size_t)8 * F);
  size_t o_fi   = alloc((size_t)4 * F);
  unsigned long long* zkey = (unsigned long long*)(ws + o_zk);
  float*  vnacc = ws + o_vn;
  float4* col   = (float4*)(ws + o_col);
  float4* frec  = (float4*)(ws + o_fr);
  float4* fbb   = (float4*)(ws + o_bb);
  float4* fe    = (float4*)(ws + o_fe);
  int4*   fidx  = (int4*)(ws + o_fi);

  // projection matrix: double math then f32 cast, matching numpy
  double fxd = 286.2057, sd = 0.0, cxd = 162.6306;
  double fyd = 286.7852, cyd = 121.0245;
  double wd = IMG_W, hd = IMG_H, ncd = 0.1, fcd = 10.0;
  double q  = -(fcd + ncd) / (fcd - ncd);
  double qn = -2.0 * fcd * ncd / (fcd - ncd);
  double Pd[16] = {
    2.0*fxd/wd, -2.0*sd/wd, (-2.0*cxd + wd)/wd, 0.0,
    0.0,        2.0*fyd/hd, (2.0*cyd - hd)/hd, -0.0,
    0.0,        0.0,        q,                  qn,
    0.0,        0.0,       -1.0,                0.0 };
  ProjM P;
  for (int i = 0; i < 16; ++i) P.m[i] = (float)Pd[i];

  int n3v = 3 * V;
  int initN = (NPX > n3v) ? NPX : n3v;
  k_init<<<(initN + 255) / 256, 256, 0, stream>>>(vnacc, n3v, zkey);
  k_face<<<(F + 63) / 64, 64, 0, stream>>>(verts, faces, pose, P, vnacc,
                                           frec, fbb, fe, fidx, F);
  k_vertex<<<(V + 63) / 64, 64, 0, stream>>>(verts, vnacc, pose, col, V);
  int nslice = (F + NSLICE - 1) / NSLICE;
  dim3 g(IMG_W / 16, IMG_H / 16, NSLICE);
  k_rasterA<<<g, 256, 0, stream>>>(frec, fbb, fe, zkey, F, nslice);
  k_resolve<<<NPX / 256, 256, 0, stream>>>(zkey, frec, col, fidx, out);
}

// Round 6
// 87.809 us; speedup vs baseline: 1.2144x; 1.0322x over previous
//
#include <hip/hip_runtime.h>
#include <math.h>

// Match numpy (no FMA fusion) for all decision-critical arithmetic.
#pragma clang fp contract(off)

#define IMG_H 240
#define IMG_W 320
#define NPX   (IMG_H * IMG_W)
#define NCH   11
#define NSLICE 4       // face-dim parallelism: grid.z slices (contiguous)
#define CULL_M 1e-3f   // conservative SAT-cull margin (e-units; |err| <~ 1e-5)
#define EZ_M   1e-5f   // early-z margin (>> 4e-7 fp bound on depth vs min(pz))

struct ProjM { float m[16]; };   // row-major numpy proj (after row-1 flip)

// One init dispatch: zero vnacc, set zkey buffer to "empty" (all 1s).
extern "C" __global__ void k_init(float* __restrict__ vnacc, int n3v,
                                  unsigned long long* __restrict__ zkey) {
  int i = blockIdx.x * 256 + threadIdx.x;
  if (i < n3v) vnacc[i] = 0.0f;
  if (i < NPX) zkey[i] = ~0ull;
}

// Shared transform helper — EXACT reference DAG (contract off).
__device__ __forceinline__ void xform(float x, float y, float z,
                                      const float* __restrict__ pose,
                                      const ProjM& P,
                                      float& px, float& py, float& pz,
                                      float& iw, float& wc) {
  float c0 = ((x*pose[0]     + y*pose[1])     + z*pose[2])     + pose[3];
  float c1 = ((x*(-pose[4])  + y*(-pose[5]))  + z*(-pose[6]))  + (-pose[7]);
  float c2 = ((x*(-pose[8])  + y*(-pose[9]))  + z*(-pose[10])) + (-pose[11]);
  float c3 = ((x*pose[12]    + y*pose[13])    + z*pose[14])    + pose[15];
  float q0 = ((c0*P.m[0]  + c1*P.m[1])  + c2*P.m[2])  + c3*P.m[3];
  float q1 = ((c0*P.m[4]  + c1*P.m[5])  + c2*P.m[6])  + c3*P.m[7];
  float q2 = ((c0*P.m[8]  + c1*P.m[9])  + c2*P.m[10]) + c3*P.m[11];
  float q3 = ((c0*P.m[12] + c1*P.m[13]) + c2*P.m[14]) + c3*P.m[15];
  wc = q3;
  float denw = (fabsf(wc) > 1e-9f) ? wc : 1e-9f;
  iw = 1.0f / denw;
  float ndx = q0 * iw, ndy = q1 * iw;
  pz = q2 * iw;
  px = ((ndx + 1.0f) * 0.5f) * (float)IMG_W;
  py = ((1.0f - ndy) * 0.5f) * (float)IMG_H;
}

// Fused per-face kernel: face-normal atomics + face setup (recomputes its 3
// corner transforms directly — bit-identical to a per-vertex pass since the
// expression DAG is identical and contraction is off).
//
// Reference's e0/e1/e2 are NOT standard barycentrics:
//   e0 = -lambda_A, e1 = -lambda_B, e2 = 2 - lambda_C; accepted region
//   {e>=0} is the triangle point-reflected through vertex C. Culling uses
//   (a) that region's bbox and (b) fp64-derived affine edge coefficients.
// frec layout (16 floats, 64 B) — eval side, reference DAG operands:
//   [0..3]  bx, by, d0=(cy-by), d1=(cx-bx)
//   [4..7]  cx, cy, d2=(ay-cy), d3=(ax-cx)
//   [8..11] inva, pz0, pz1, pz2
//   [12..15] iw0, iw1, iw2, 0
extern "C" __global__ void k_face(const float* __restrict__ verts,
                                  const int* __restrict__ faces,
                                  const float* __restrict__ pose,
                                  ProjM P,
                                  float* __restrict__ vnacc,
                                  float4* __restrict__ frec,
                                  float4* __restrict__ fbb,
                                  float4* __restrict__ fe,
                                  int4*  __restrict__ fidx, int F) {
  int f = blockIdx.x * 64 + threadIdx.x;
  if (f >= F) return;
  int i0 = faces[3*f+0], i1 = faces[3*f+1], i2 = faces[3*f+2];
  float x0 = verts[3*i0+0], y0 = verts[3*i0+1], z0 = verts[3*i0+2];
  float x1 = verts[3*i1+0], y1 = verts[3*i1+1], z1 = verts[3*i1+2];
  float x2 = verts[3*i2+0], y2 = verts[3*i2+1], z2 = verts[3*i2+2];

  // ---- face normal accumulation (unchanged DAG) ----
  {
    float ux = x1 - x0, uy = y1 - y0, uz = z1 - z0;
    float vx = x2 - x0, vy = y2 - y0, vz = z2 - z0;
    float fx = uy*vz - uz*vy;
    float fy = uz*vx - ux*vz;
    float fz = ux*vy - uy*vx;
    float n = sqrtf((fx*fx + fy*fy) + fz*fz);
    float d = fmaxf(n, 1e-12f);
    fx = fx / d; fy = fy / d; fz = fz / d;
    atomicAdd(&vnacc[3*i0+0], fx); atomicAdd(&vnacc[3*i0+1], fy); atomicAdd(&vnacc[3*i0+2], fz);
    atomicAdd(&vnacc[3*i1+0], fx); atomicAdd(&vnacc[3*i1+1], fy); atomicAdd(&vnacc[3*i1+2], fz);
    atomicAdd(&vnacc[3*i2+0], fx); atomicAdd(&vnacc[3*i2+1], fy); atomicAdd(&vnacc[3*i2+2], fz);
  }

  // ---- corner transforms (identical DAG to reference vertex path) ----
  float ax, ay, pz0, iw0, w0;  xform(x0, y0, z0, pose, P, ax, ay, pz0, iw0, w0);
  float bx, by, pz1, iw1, w1;  xform(x1, y1, z1, pose, P, bx, by, pz1, iw1, w1);
  float cx, cy, pz2, iw2, w2;  xform(x2, y2, z2, pose, P, cx, cy, pz2, iw2, w2);

  float area = (bx - ax) * (cy - ay) - (by - ay) * (cx - ax);
  float inva = 1.0f / ((fabsf(area) > 1e-12f) ? area : 1e-12f);
  bool valid = (w0 > 1e-6f) && (w1 > 1e-6f) && (w2 > 1e-6f) && (fabsf(area) > 1e-12f);
  // reflected-triangle vertices {C, 2C-A, 2C-B}
  float rax = 2.0f*cx - ax, ray = 2.0f*cy - ay;
  float rbx = 2.0f*cx - bx, rby = 2.0f*cy - by;
  float minx = fminf(cx, fminf(rax, rbx)), maxx = fmaxf(cx, fmaxf(rax, rbx));
  float miny = fminf(cy, fminf(ray, rby)), maxy = fmaxf(cy, fmaxf(ray, rby));
  frec[4*f+0] = make_float4(bx, by, cy - by, cx - bx);
  frec[4*f+1] = make_float4(cx, cy, ay - cy, ax - cx);
  frec[4*f+2] = make_float4(inva, pz0, pz1, pz2);
  frec[4*f+3] = make_float4(iw0, iw1, iw2, 0.0f);
  fbb[f] = valid ? make_float4(minx, maxx, miny, maxy)
                 : make_float4(1e30f, -1e30f, 1e30f, -1e30f);
  fidx[f] = make_int4(i0, i1, i2, 0);
  // affine edge coefficients, fp64 for tight error:
  //   e0 = ((X-bx)*d0 - (Y-by)*d1)*inva = a0*X + b0*Y + c0
  {
    double dbx = bx, dby = by, dcx = cx, dcy = cy, dax = ax, day = ay;
    double dinv = (double)inva;
    double d0 = dcy - dby, d1 = dcx - dbx;
    double d2 = day - dcy, d3 = dax - dcx;
    double a0 = d0 * dinv, b0 = -d1 * dinv, c0 = (dby * d1 - dbx * d0) * dinv;
    double a1 = d2 * dinv, b1 = -d3 * dinv, c1 = (dcy * d3 - dcx * d2) * dinv;
    fe[2*f+0] = make_float4((float)a0, (float)b0, (float)c0, 0.0f);
    fe[2*f+1] = make_float4((float)a1, (float)b1, (float)c1, 0.0f);
  }
}

// Pass A: 16x16 pixel region per 256-thread block (4 waves x 8x8 subtiles),
// face-slice on grid.z (contiguous ranges, F/NSLICE each).
//
// HIERARCHICAL CULL (round-5 lesson: rasterA is throughput-bound on total
// cull work; the old scheme tested every (face, 8x8-subtile) pair = 4x
// redundant within a block). Per 256-face batch:
//   Phase 1: thread t tests face base+t against the BLOCK's 16x16 rect
//     (bbox + SAT extrema over the block rect — conservative for every
//     sub-rect since extrema over a superset bound extrema over subsets).
//     Survivors compacted ORDER-PRESERVING into an LDS list (wave-count
//     prefix + popc within wave) -> each (face, tile) tested once.
//   Phase 2: each wave sweeps the survivor list in 64-chunks against its
//     own 8x8 subtile (bbox + SAT, L2-warm loads), ballot -> pair-unrolled
//     eval loop (both C records issued together; early-z ballot gate on
//     conservative min of the pair; then both A/B pairs — halves exposed
//     scalar-load latency).
// Ascending face order is preserved through compaction and eval, so the
// strict-< accept keeps the reference's chunk-argmin + strict-< carry
// semantics. Winner = lexicographic min of (depth, face index) via packed
// u64 atomicMin — smaller index wins exact ties across slices too.
extern "C" __global__ __launch_bounds__(256)
void k_rasterA(const float4* __restrict__ frec,
               const float4* __restrict__ fbb,
               const float4* __restrict__ fe,
               unsigned long long* __restrict__ zkey,
               int F, int nslice) {
  __shared__ int sList[256];
  __shared__ int sWaveCnt[4];
  int t = threadIdx.x;
  int wave = t >> 6;                  // 0..3
  int lane = t & 63;
  int sx = (wave & 1) * 8, sy = (wave >> 1) * 8;
  int pxi = blockIdx.x * 16 + sx + (lane & 7);
  int pyi = blockIdx.y * 16 + sy + (lane >> 3);
  float X = (float)pxi + 0.5f;
  float Y = (float)pyi + 0.5f;
  // wave's 8x8 subtile rect
  float tXlo = (float)(blockIdx.x * 16 + sx) + 0.5f, tXhi = tXlo + 7.0f;
  float tYlo = (float)(blockIdx.y * 16 + sy) + 0.5f, tYhi = tYlo + 7.0f;
  // block's 16x16 rect
  float bXlo = (float)(blockIdx.x * 16) + 0.5f, bXhi = bXlo + 15.0f;
  float bYlo = (float)(blockIdx.y * 16) + 0.5f, bYhi = bYlo + 15.0f;

  int f0 = blockIdx.z * nslice;
  int f1 = min(F, f0 + nslice);

  float bestd = 1e9f;
  int   besti = -1;

  for (int base = f0; base < f1; base += 256) {
    // ---- phase 1: block-level cull, one face per thread ----
    int f = base + t;
    bool bp = false;
    if (f < f1) {
      float4 bb = fbb[f];
      bp = (bb.x - 1.0f <= bXhi) && (bb.y + 1.0f >= bXlo) &&
           (bb.z - 1.0f <= bYhi) && (bb.w + 1.0f >= bYlo);
      if (bp) {
        float4 E0 = fe[2*f+0];
        float4 E1 = fe[2*f+1];
        float pa0 = E0.x * bXlo, pb0 = E0.x * bXhi;
        float qa0 = E0.y * bYlo, qb0 = E0.y * bYhi;
        float e0mx = (fmaxf(pa0, pb0) + fmaxf(qa0, qb0)) + E0.z;
        float e0mn = (fminf(pa0, pb0) + fminf(qa0, qb0)) + E0.z;
        float pa1 = E1.x * bXlo, pb1 = E1.x * bXhi;
        float qa1 = E1.y * bYlo, qb1 = E1.y * bYhi;
        float e1mx = (fmaxf(pa1, pb1) + fmaxf(qa1, qb1)) + E1.z;
        float e1mn = (fminf(pa1, pb1) + fminf(qa1, qb1)) + E1.z;
        float e2mx = (1.0f - e0mn) - e1mn;   // upper bound of e2
        bp = (e0mx >= -CULL_M) && (e1mx >= -CULL_M) && (e2mx >= -CULL_M);
      }
    }
    unsigned long long wm = __ballot(bp);
    if (lane == 0) sWaveCnt[wave] = __popcll(wm);
    __syncthreads();
    int c0 = sWaveCnt[0], c1 = sWaveCnt[1], c2 = sWaveCnt[2], c3 = sWaveCnt[3];
    int tot = ((c0 + c1) + c2) + c3;
    if (bp) {
      int off = (wave > 0 ? c0 : 0) + (wave > 1 ? c1 : 0) + (wave > 2 ? c2 : 0);
      int pos = off + __popcll(wm & ((1ull << lane) - 1ull));
      sList[pos] = f;          // ascending face order preserved
    }
    __syncthreads();

    // ---- phase 2: per-wave subtile cull over survivor list + eval ----
    for (int k0 = 0; k0 < tot; k0 += 64) {
      int k = k0 + lane;
      bool ov = false;
      int fi = 0;
      if (k < tot) {
        fi = sList[k];
        float4 bb = fbb[fi];
        ov = (bb.x - 1.0f <= tXhi) && (bb.y + 1.0f >= tXlo) &&
             (bb.z - 1.0f <= tYhi) && (bb.w + 1.0f >= tYlo);
        if (ov) {
          float4 E0 = fe[2*fi+0];
          float4 E1 = fe[2*fi+1];
          float pa0 = E0.x * tXlo, pb0 = E0.x * tXhi;
          float qa0 = E0.y * tYlo, qb0 = E0.y * tYhi;
          float e0mx = (fmaxf(pa0, pb0) + fmaxf(qa0, qb0)) + E0.z;
          float e0mn = (fminf(pa0, pb0) + fminf(qa0, qb0)) + E0.z;
          float pa1 = E1.x * tXlo, pb1 = E1.x * tXhi;
          float qa1 = E1.y * tYlo, qb1 = E1.y * tYhi;
          float e1mx = (fmaxf(pa1, pb1) + fmaxf(qa1, qb1)) + E1.z;
          float e1mn = (fminf(pa1, pb1) + fminf(qa1, qb1)) + E1.z;
          float e2mx = (1.0f - e0mn) - e1mn;
          ov = (e0mx >= -CULL_M) && (e1mx >= -CULL_M) && (e2mx >= -CULL_M);
        }
      }
      unsigned long long mask = __ballot(ov);

      while (mask) {
        int j0 = __builtin_ctzll(mask);
        mask &= mask - 1;
        bool two = (mask != 0ull);
        int j1 = two ? __builtin_ctzll(mask) : j0;   // pad with duplicate
        if (two) mask &= mask - 1;

        int ju0 = __builtin_amdgcn_readfirstlane(__shfl(fi, j0));
        int ju1 = __builtin_amdgcn_readfirstlane(__shfl(fi, j1));
        const float4* fr0 = frec + (size_t)ju0 * 4;
        const float4* fr1 = frec + (size_t)ju1 * 4;
        // issue both depth records together (latency overlap)
        float4 C0 = fr0[2];   // inva, pz0, pz1, pz2
        float4 C1 = fr1[2];
        // early-z: skip only if BOTH faces provably lose for every lane
        float zmin0 = fminf(C0.y, fminf(C0.z, C0.w));
        float zmin1 = fminf(C1.y, fminf(C1.z, C1.w));
        float zmg = two ? fminf(zmin0, zmin1) : zmin0;
        if (__ballot(bestd > zmg - EZ_M) == 0ull) continue;
        float4 A0 = fr0[0], B0 = fr0[1];
        float4 A1 = fr1[0], B1 = fr1[1];

        {
          float t0 = (X - A0.x) * A0.z;
          float t1 = (Y - A0.y) * A0.w;
          float e0 = (t0 - t1) * C0.x;
          float t2 = (X - B0.x) * B0.z;
          float t3 = (Y - B0.y) * B0.w;
          float e1 = (t2 - t3) * C0.x;
          float e2 = (1.0f - e0) - e1;
          float depth = ((e0 * C0.y) + (e1 * C0.z)) + (e2 * C0.w);
          bool inside = (e0 >= 0.0f) && (e1 >= 0.0f) && (e2 >= 0.0f) &&
                        (depth >= -1.0f) && (depth <= 1.0f);
          if (inside && depth < bestd) { bestd = depth; besti = ju0; }
        }
        if (two) {
          float t0 = (X - A1.x) * A1.z;
          float t1 = (Y - A1.y) * A1.w;
          float e0 = (t0 - t1) * C1.x;
          float t2 = (X - B1.x) * B1.z;
          float t3 = (Y - B1.y) * B1.w;
          float e1 = (t2 - t3) * C1.x;
          float e2 = (1.0f - e0) - e1;
          float depth = ((e0 * C1.y) + (e1 * C1.z)) + (e2 * C1.w);
          bool inside = (e0 >= 0.0f) && (e1 >= 0.0f) && (e2 >= 0.0f) &&
                        (depth >= -1.0f) && (depth <= 1.0f);
          if (inside && depth < bestd) { bestd = depth; besti = ju1; }
        }
      }
    }
    __syncthreads();   // protect sList/sWaveCnt before next batch
  }

  if (besti >= 0) {
    unsigned int ub = __float_as_uint(bestd);
    ub = (ub & 0x80000000u) ? ~ub : (ub | 0x80000000u);   // order-preserving
    unsigned long long key = ((unsigned long long)ub << 32) | (unsigned int)besti;
    atomicMin(&zkey[(size_t)pyi * IMG_W + pxi], key);
  }
}

// Pass B: per-pixel resolve — recompute winner's barycentrics (same DAG as
// rasterA) and compute the 3 winner-vertex colors INLINE (bit-identical DAG
// to the old k_vertex — verified in rounds 3/4; kills that dispatch and the
// colors buffer). Stage in LDS, write fully-coalesced float4s.
extern "C" __global__ __launch_bounds__(256)
void k_resolve(const unsigned long long* __restrict__ zkey,
               const float4* __restrict__ frec,
               const int4* __restrict__ fidx,
               const float* __restrict__ verts,
               const float* __restrict__ vnacc,
               const float* __restrict__ pose,
               float* __restrict__ out) {
  __shared__ float sOut[256 * NCH];   // 11 KB
  int t = threadIdx.x;
  int p = blockIdx.x * 256 + t;       // NPX = 300 * 256 exactly
  int pyi = p / IMG_W, pxi = p - pyi * IMG_W;
  float X = (float)pxi + 0.5f;
  float Y = (float)pyi + 0.5f;
  unsigned long long key = zkey[p];

  float oc[NCH];
  if (key != ~0ull) {
    int besti = (int)(key & 0xFFFFFFFFu);
    const float4* fr = frec + (size_t)besti * 4;
    float4 A = fr[0], B = fr[1], C = fr[2], D = fr[3];
    float t0 = (X - A.x) * A.z;
    float t1 = (Y - A.y) * A.w;
    float e0 = (t0 - t1) * C.x;
    float t2 = (X - B.x) * B.z;
    float t3 = (Y - B.y) * B.w;
    float e1 = (t2 - t3) * C.x;
    float b2 = (1.0f - e0) - e1;
    float p0 = e0 * D.x, p1 = e1 * D.y, p2 = b2 * D.z;
    float den = (p0 + p1) + p2;
    if (!(fabsf(den) > 1e-12f)) den = 1e-12f;
    float u0 = p0 / den, u1 = p1 / den, u2 = p2 / den;
    int4 vi = fidx[besti];

    // inline vertex colors (exact old-k_vertex DAG), 3 vertices
    float cv[3][NCH];
    int vids[3] = { vi.x, vi.y, vi.z };
    #pragma unroll
    for (int k = 0; k < 3; ++k) {
      int id = vids[k];
      float x = verts[3*id+0], y = verts[3*id+1], z = verts[3*id+2];
      float nx = vnacc[3*id+0], ny = vnacc[3*id+1], nz = vnacc[3*id+2];
      float nn = sqrtf((nx*nx + ny*ny) + nz*nz);
      float nm = fmaxf(nn, 1e-12f);
      nx = nx / nm; ny = ny / nm; nz = nz / nm;
      float v3x = ((x*pose[0] + y*pose[1]) + z*pose[2])  + pose[3];
      float v3y = ((x*pose[4] + y*pose[5]) + z*pose[6])  + pose[7];
      float v3z = ((x*pose[8] + y*pose[9]) + z*pose[10]) + pose[11];
      cv[k][0] = 1.0f;  cv[k][1] = v3x; cv[k][2] = v3y; cv[k][3] = v3z;
      cv[k][4] = nx;    cv[k][5] = ny;  cv[k][6] = nz;
      cv[k][7] = x;     cv[k][8] = y;   cv[k][9] = z;   cv[k][10] = 1.0f;
    }
    #pragma unroll
    for (int ch = 0; ch < NCH; ++ch)
      oc[ch] = (u0 * cv[0][ch] + u1 * cv[1][ch]) + u2 * cv[2][ch];
  } else {
    #pragma unroll
    for (int ch = 0; ch < NCH; ++ch) oc[ch] = 0.0f;
  }
  #pragma unroll
  for (int ch = 0; ch < NCH; ++ch) sOut[t * NCH + ch] = oc[ch];
  __syncthreads();
  // 256*11 = 2816 floats = 704 float4s, contiguous; block offset 16B-aligned
  float4* o4 = (float4*)(out + (size_t)blockIdx.x * 256 * NCH);
  const float4* s4 = (const float4*)sOut;
  #pragma unroll
  for (int k = 0; k < 3; ++k) {
    int idx = t + k * 256;
    if (idx < 704) o4[idx] = s4[idx];
  }
}

extern "C" void kernel_launch(void* const* d_in, const int* in_sizes, int n_in,
                              void* d_out, int out_size, void* d_ws, size_t ws_size,
                              hipStream_t stream) {
  const float* verts = (const float*)d_in[0];
  const int*   faces = (const int*)d_in[1];
  const float* pose  = (const float*)d_in[2];
  float* out = (float*)d_out;
  int V = in_sizes[0] / 3;
  int F = in_sizes[1] / 3;

  // workspace layout (float units, 16B-aligned chunks)
  float* ws = (float*)d_ws;
  size_t o = 0;
  auto alloc = [&](size_t n) { size_t r = o; o += (n + 3) & ~(size_t)3; return r; };
  size_t o_zk   = alloc((size_t)2 * NPX);     // u64 zkey buffer
  size_t o_vn   = alloc((size_t)3 * V);
  size_t o_fr   = alloc((size_t)16 * F);
  size_t o_bb   = alloc((size_t)4 * F);
  size_t o_fe   = alloc((size_t)8 * F);
  size_t o_fi   = alloc((size_t)4 * F);
  unsigned long long* zkey = (unsigned long long*)(ws + o_zk);
  float*  vnacc = ws + o_vn;
  float4* frec  = (float4*)(ws + o_fr);
  float4* fbb   = (float4*)(ws + o_bb);
  float4* fe    = (float4*)(ws + o_fe);
  int4*   fidx  = (int4*)(ws + o_fi);

  // projection matrix: double math then f32 cast, matching numpy
  double fxd = 286.2057, sd = 0.0, cxd = 162.6306;
  double fyd = 286.7852, cyd = 121.0245;
  double wd = IMG_W, hd = IMG_H, ncd = 0.1, fcd = 10.0;
  double q  = -(fcd + ncd) / (fcd - ncd);
  double qn = -2.0 * fcd * ncd / (fcd - ncd);
  double Pd[16] = {
    2.0*fxd/wd, -2.0*sd/wd, (-2.0*cxd + wd)/wd, 0.0,
    0.0,        2.0*fyd/hd, (2.0*cyd - hd)/hd, -0.0,
    0.0,        0.0,        q,                  qn,
    0.0,        0.0,       -1.0,                0.0 };
  ProjM P;
  for (int i = 0; i < 16; ++i) P.m[i] = (float)Pd[i];

  int n3v = 3 * V;
  int initN = (NPX > n3v) ? NPX : n3v;
  k_init<<<(initN + 255) / 256, 256, 0, stream>>>(vnacc, n3v, zkey);
  k_face<<<(F + 63) / 64, 64, 0, stream>>>(verts, faces, pose, P, vnacc,
                                           frec, fbb, fe, fidx, F);
  int nslice = (F + NSLICE - 1) / NSLICE;
  dim3 g(IMG_W / 16, IMG_H / 16, NSLICE);
  k_rasterA<<<g, 256, 0, stream>>>(frec, fbb, fe, zkey, F, nslice);
  k_resolve<<<NPX / 256, 256, 0, stream>>>(zkey, frec, fidx, verts, vnacc,
                                           pose, out);
}